// Round 3
// baseline (346.610 us; speedup 1.0000x reference)
//
#include <hip/hip_runtime.h>
#include <math.h>

#define INV_SQRT2F 0.7071067811865476f

#define GRID_BLOCKS   1024
#define BLOCK_THREADS 256
#define NTHREADS      (GRID_BLOCKS * BLOCK_THREADS)   // 262144; n4 = NTHREADS*16

// ws float layout:
//   [0..1023]    s1 partials (per-block slot, plain overwrite of poison)
//   [1024..2047] s2 partials
//   [2048..3071] erf partials
//   [3072]       barrier counter 1 (uint)   } memset-zeroed 128 B region
//   [3088]       barrier counter 2 (uint)   }
#define S1_BASE 0
#define S2_BASE 1024
#define SE_BASE 2048
#define C_BASE  3072
#define C1_IDX  3072
#define C2_IDX  3088

// R2 post-mortem: cg::grid_group::sync() under graph capture hung the GPU
// (container died twice). This version does the SAME fusion with a manual
// device-scope atomic barrier — no cooperative API, no hidden runtime state.
// Co-residency guarantee: __launch_bounds__(256,4) -> >=4 waves/EU ->
// 4 WG/CU * 256 CU = 1024 blocks resident; grid is exactly 1024.

__device__ __forceinline__ float aload(const float* p) {
    return __hip_atomic_load(p, __ATOMIC_RELAXED, __HIP_MEMORY_SCOPE_AGENT);
}
__device__ __forceinline__ void astore(float* p, float v) {
    __hip_atomic_store(p, v, __ATOMIC_RELAXED, __HIP_MEMORY_SCOPE_AGENT);
}

__global__ void __launch_bounds__(BLOCK_THREADS, 4)
fused(const float4* __restrict__ pred4, const float4* __restrict__ targ4,
      int n, float* __restrict__ ws, float* __restrict__ out)
{
    const int gtid = blockIdx.x * BLOCK_THREADS + threadIdx.x;
    const int lane = threadIdx.x & 63;
    const int wid  = threadIdx.x >> 6;
    unsigned int* c1 = (unsigned int*)&ws[C1_IDX];
    unsigned int* c2 = (unsigned int*)&ws[C2_IDX];

    // ---- Phase 1: load once; d stays in registers (all indices static) ----
    float d[64];
    float s1 = 0.f, s2 = 0.f;

#pragma unroll
    for (int c = 0; c < 8; ++c) {            // 8 clusters x (2 pred + 2 targ) dwordx4
        float4 p0 = pred4[gtid + (c * 2 + 0) * NTHREADS];
        float4 p1 = pred4[gtid + (c * 2 + 1) * NTHREADS];
        float4 t0 = targ4[gtid + (c * 2 + 0) * NTHREADS];
        float4 t1 = targ4[gtid + (c * 2 + 1) * NTHREADS];
        __builtin_amdgcn_sched_barrier(0);   // 4 loads in flight before any use
        const int k = c * 8;
        d[k + 0] = fabsf(p0.x - t0.x);
        d[k + 1] = fabsf(p0.y - t0.y);
        d[k + 2] = fabsf(p0.z - t0.z);
        d[k + 3] = fabsf(p0.w - t0.w);
        d[k + 4] = fabsf(p1.x - t1.x);
        d[k + 5] = fabsf(p1.y - t1.y);
        d[k + 6] = fabsf(p1.z - t1.z);
        d[k + 7] = fabsf(p1.w - t1.w);
#pragma unroll
        for (int j = 0; j < 8; ++j) {
            s1 += d[k + j];
            s2 += d[k + j] * d[k + j];
        }
    }

    // block reduce s1,s2 -> per-block slots, then arrive at barrier 1
    for (int off = 32; off > 0; off >>= 1) {
        s1 += __shfl_down(s1, off);
        s2 += __shfl_down(s2, off);
    }
    __shared__ float ls1[4], ls2[4];
    if (lane == 0) { ls1[wid] = s1; ls2[wid] = s2; }
    __syncthreads();
    if (threadIdx.x == 0) {
        astore(&ws[S1_BASE + blockIdx.x], (ls1[0] + ls1[1]) + (ls1[2] + ls1[3]));
        astore(&ws[S2_BASE + blockIdx.x], (ls2[0] + ls2[1]) + (ls2[2] + ls2[3]));
        __hip_atomic_fetch_add(c1, 1u, __ATOMIC_RELEASE, __HIP_MEMORY_SCOPE_AGENT);
        // spin until all 1024 blocks have arrived
        while (__hip_atomic_load(c1, __ATOMIC_ACQUIRE, __HIP_MEMORY_SCOPE_AGENT)
               < (unsigned)GRID_BLOCKS)
            __builtin_amdgcn_s_sleep(1);
    }
    __syncthreads();
    // every thread takes its own acquire edge (syncthreads alone is workgroup-scope)
    (void)__hip_atomic_load(c1, __ATOMIC_ACQUIRE, __HIP_MEMORY_SCOPE_AGENT);

    // ---- all threads gather the 1024 partials (4 loads each) ----
    float g1 = 0.f, g2 = 0.f;
#pragma unroll
    for (int q = 0; q < 4; ++q) {
        g1 += aload(&ws[S1_BASE + threadIdx.x + 256 * q]);
        g2 += aload(&ws[S2_BASE + threadIdx.x + 256 * q]);
    }
    for (int off = 32; off > 0; off >>= 1) {
        g1 += __shfl_down(g1, off);
        g2 += __shfl_down(g2, off);
    }
    __shared__ float gs1[4], gs2[4];
    if (lane == 0) { gs1[wid] = g1; gs2[wid] = g2; }
    __syncthreads();
    float sum_d  = (gs1[0] + gs1[1]) + (gs1[2] + gs1[3]);
    float sum_d2 = (gs2[0] + gs2[1]) + (gs2[2] + gs2[3]);

    float nf     = (float)n;
    float mean_d = sum_d / nf;
    float var    = (sum_d2 - sum_d * mean_d) / (nf - 1.0f);
    float kk     = INV_SQRT2F / var;

    // ---- Phase 2: erf over in-register d — zero memory re-read ----
    float s = 0.f;
#pragma unroll
    for (int e = 0; e < 16; ++e) {
        s += (erff(d[4 * e + 0] * kk) + erff(d[4 * e + 1] * kk))
           + (erff(d[4 * e + 2] * kk) + erff(d[4 * e + 3] * kk));
    }
    for (int off = 32; off > 0; off >>= 1)
        s += __shfl_down(s, off);
    __shared__ float es[4];
    if (lane == 0) es[wid] = s;
    __syncthreads();
    if (threadIdx.x == 0) {
        astore(&ws[SE_BASE + blockIdx.x], (es[0] + es[1]) + (es[2] + es[3]));
        __hip_atomic_fetch_add(c2, 1u, __ATOMIC_RELEASE, __HIP_MEMORY_SCOPE_AGENT);
    }

    // ---- block 0 alone waits for erf partials, reduces, writes out ----
    if (blockIdx.x == 0) {
        if (threadIdx.x == 0) {
            while (__hip_atomic_load(c2, __ATOMIC_ACQUIRE, __HIP_MEMORY_SCOPE_AGENT)
                   < (unsigned)GRID_BLOCKS)
                __builtin_amdgcn_s_sleep(1);
        }
        __syncthreads();
        (void)__hip_atomic_load(c2, __ATOMIC_ACQUIRE, __HIP_MEMORY_SCOPE_AGENT);

        float se = 0.f;
#pragma unroll
        for (int q = 0; q < 4; ++q)
            se += aload(&ws[SE_BASE + threadIdx.x + 256 * q]);
        for (int off = 32; off > 0; off >>= 1)
            se += __shfl_down(se, off);
        __shared__ float fs[4];
        if (lane == 0) fs[wid] = se;
        __syncthreads();
        if (threadIdx.x == 0) {
            float sum_erf = (fs[0] + fs[1]) + (fs[2] + fs[3]);
            float p       = 1.0f - sum_erf / nf;          // p_correct
            float gamma   = -logf(p);
            float coef    = expf(gamma * logf(1.0f - p)); // (1-p)^gamma
            out[0] = coef * mean_d + logf(var + 1.0f);    // LOSS_WEIGHT = 1
        }
    }
}

extern "C" void kernel_launch(void* const* d_in, const int* in_sizes, int n_in,
                              void* d_out, int out_size, void* d_ws, size_t ws_size,
                              hipStream_t stream) {
    const float4* pred4 = (const float4*)d_in[0];
    const float4* targ4 = (const float4*)d_in[1];
    float* out = (float*)d_out;
    float* ws  = (float*)d_ws;
    int n = in_sizes[0];         // 16777216; n4 = 4194304 = NTHREADS * 16

    // zero ONLY the barrier counters (partial slots are plain-overwritten)
    hipMemsetAsync((char*)d_ws + C_BASE * sizeof(float), 0, 128, stream);

    fused<<<GRID_BLOCKS, BLOCK_THREADS, 0, stream>>>(pred4, targ4, n, ws, out);
}